// Round 3
// baseline (1154.538 us; speedup 1.0000x reference)
//
#include <hip/hip_runtime.h>
#include <hip/hip_bf16.h>

// Problem constants
constexpr int B_ = 8;
constexpr int L_ = 2048;
constexpr int C_ = 512;
constexpr int R_ = 64;
constexpr int DK_ = 64;
constexpr int H_ = 1024;   // 2*C
constexpr int M_ = B_ * L_;  // 16384
constexpr float NEG_ = -32767.0f;

__device__ __forceinline__ float toF(float x) { return x; }
__device__ __forceinline__ float toF(__hip_bfloat16 x) { return __bfloat162float(x); }
__device__ __forceinline__ float siluf(float v) { return v / (1.0f + __expf(-v)); }

// ---------------------------------------------------------------------------
// Generic 64x64 tiled GEMM, BK=16, 256 threads, 4x4 micro-tile per thread.
// EPI: 0 = bias + silu -> bf16 out (gate)
//      1 = bias, apply maskPAD (row==0 -> NEG), store f32 (pScore)
//      2 = bias + residual (RT) -> bf16 out (pre-layernorm y)
//      3 = multiply by resid (RT, same buffer as outB, elementwise in-place)
// ---------------------------------------------------------------------------
template <typename AT, typename BT, typename RT, int ACT, int EPI>
__global__ __launch_bounds__(256) void gemm64(
    const AT* __restrict__ A, const BT* __restrict__ Bw,
    const float* __restrict__ bias,
    const int* __restrict__ mask,
    const RT* resid,
    float* __restrict__ outF, __hip_bfloat16* outB,
    int Ndim, int Kdim, long bBatchStride)
{
    __shared__ float As[16][68];   // transposed A tile: As[k][m]
    __shared__ float Bs[16][64];   // Bs[k][n]
    const int tid = threadIdx.x;
    const int tx = tid & 15, ty = tid >> 4;
    const int n0 = blockIdx.x * 64, m0 = blockIdx.y * 64;
    const BT* Bp = Bw + (bBatchStride ? (long)(m0 / L_) * bBatchStride : 0);

    float acc[4][4] = {};

    for (int k0 = 0; k0 < Kdim; k0 += 16) {
#pragma unroll
        for (int s = 0; s < 4; ++s) {
            int idx = tid + s * 256;          // 64x16 = 1024 elems
            int am = idx >> 4, ak = idx & 15;
            As[ak][am] = toF(A[(size_t)(m0 + am) * Kdim + k0 + ak]);
        }
#pragma unroll
        for (int s = 0; s < 4; ++s) {
            int idx = tid + s * 256;          // 16x64 = 1024 elems
            int bk = idx >> 6, bn = idx & 63;
            Bs[bk][bn] = toF(Bp[(size_t)(k0 + bk) * Ndim + n0 + bn]);
        }
        __syncthreads();
#pragma unroll
        for (int kk = 0; kk < 16; ++kk) {
            float av[4], bv[4];
            *(float4*)av = *(const float4*)&As[kk][ty * 4];
            *(float4*)bv = *(const float4*)&Bs[kk][tx * 4];
#pragma unroll
            for (int i = 0; i < 4; ++i)
#pragma unroll
                for (int j = 0; j < 4; ++j) acc[i][j] += av[i] * bv[j];
        }
        __syncthreads();
    }

#pragma unroll
    for (int i = 0; i < 4; ++i) {
        int m = m0 + ty * 4 + i;
#pragma unroll
        for (int j = 0; j < 4; ++j) {
            int n = n0 + tx * 4 + j;
            float val = acc[i][j];
            if (EPI != 3) val += bias[n];
            if (ACT) val = siluf(val);
            if (EPI == 0) {
                outB[(size_t)m * Ndim + n] = __float2bfloat16(val);
            } else if (EPI == 1) {
                if (mask[m] == 0) val = NEG_;
                outF[(size_t)m * Ndim + n] = val;
            } else if (EPI == 2) {
                val += toF(resid[(size_t)m * Ndim + n]);
                outB[(size_t)m * Ndim + n] = __float2bfloat16(val);
            } else {
                val *= toF(resid[(size_t)m * Ndim + n]);
                outB[(size_t)m * Ndim + n] = __float2bfloat16(val);
            }
        }
    }
}

// softmax over L (axis=1). One block per (b, r). pScore strided by R.
__global__ __launch_bounds__(256) void softmaxL(const float* __restrict__ pScore,
                                                float* __restrict__ pAlpha)
{
    const int b = blockIdx.x >> 6, r = blockIdx.x & 63;
    const int t = threadIdx.x;
    const float* base = pScore + (size_t)b * L_ * R_ + r;
    float* out = pAlpha + (size_t)b * L_ * R_ + r;
    __shared__ float red[256];

    float mx = -3.4e38f;
    for (int l = t; l < L_; l += 256) mx = fmaxf(mx, base[(size_t)l * R_]);
    red[t] = mx; __syncthreads();
    for (int s = 128; s > 0; s >>= 1) { if (t < s) red[t] = fmaxf(red[t], red[t + s]); __syncthreads(); }
    mx = red[0]; __syncthreads();

    float sum = 0.f;
    for (int l = t; l < L_; l += 256) {
        float e = __expf(base[(size_t)l * R_] - mx);
        out[(size_t)l * R_] = e;
        sum += e;
    }
    red[t] = sum; __syncthreads();
    for (int s = 128; s > 0; s >>= 1) { if (t < s) red[t] += red[t + s]; __syncthreads(); }
    const float inv = 1.0f / red[0];
    for (int l = t; l < L_; l += 256) out[(size_t)l * R_] *= inv;
}

// softmax over r (axis=-1). One 64-thread wave per row m.
__global__ __launch_bounds__(64) void softmaxR(const float* __restrict__ pScore,
                                               float* __restrict__ pAlphaR)
{
    const size_t m = blockIdx.x;
    const int t = threadIdx.x;
    float v = pScore[m * R_ + t];
    float mx = v;
#pragma unroll
    for (int o = 32; o > 0; o >>= 1) mx = fmaxf(mx, __shfl_xor(mx, o, 64));
    float e = __expf(v - mx);
    float s = e;
#pragma unroll
    for (int o = 32; o > 0; o >>= 1) s += __shfl_xor(s, o, 64);
    pAlphaR[m * R_ + t] = e / s;
}

// px[b,r,c] = sum_l pAlpha[b,l,r] * x[b,l,c].  One block per (b,r).
__global__ __launch_bounds__(256) void compress(const float* __restrict__ pAlpha,
                                                const float* __restrict__ x,
                                                float* __restrict__ px)
{
    const int b = blockIdx.x >> 6, r = blockIdx.x & 63;
    const int t = threadIdx.x;
    const float* pa = pAlpha + (size_t)b * L_ * R_ + r;
    const float* xb = x + (size_t)b * L_ * C_;
    float a0 = 0.f, a1 = 0.f;
#pragma unroll 4
    for (int l = 0; l < L_; ++l) {
        float a = pa[(size_t)l * R_];          // wave-uniform scalar load
        a0 += a * xb[(size_t)l * C_ + t];
        a1 += a * xb[(size_t)l * C_ + t + 256];
    }
    px[((size_t)b * R_ + r) * C_ + t] = a0;
    px[((size_t)b * R_ + r) * C_ + t + 256] = a1;
}

// q/k/v = silu(px @ W* + b*). One block per (b,r) row of px.
__global__ __launch_bounds__(256) void qkv(
    const float* __restrict__ px,
    const float* __restrict__ Wq, const float* __restrict__ bq,
    const float* __restrict__ Wk, const float* __restrict__ bk,
    const float* __restrict__ Wv, const float* __restrict__ bv,
    float* __restrict__ q, float* __restrict__ k, float* __restrict__ v)
{
    __shared__ float xr[C_];
    const int row = blockIdx.x;
    const int t = threadIdx.x;
    xr[t] = px[(size_t)row * C_ + t];
    xr[t + 256] = px[(size_t)row * C_ + t + 256];
    __syncthreads();
    for (int o = t; o < 2 * DK_ + H_; o += 256) {
        const float* W; const float* bb; float* dst; int n, N;
        if (o < DK_)            { W = Wq; bb = bq; dst = q; n = o;           N = DK_; }
        else if (o < 2 * DK_)   { W = Wk; bb = bk; dst = k; n = o - DK_;     N = DK_; }
        else                    { W = Wv; bb = bv; dst = v; n = o - 2 * DK_; N = H_;  }
        float acc = bb[n];
        for (int c = 0; c < C_; ++c) acc += xr[c] * W[(size_t)c * N + n];
        dst[(size_t)row * N + n] = siluf(acc);
    }
}

// scores + softmax -> alpha.  One 64-thread wave per (b,r); lane = s.
__global__ __launch_bounds__(64) void attn_scores(
    const float* __restrict__ q, const float* __restrict__ k,
    const float* __restrict__ preS, float* __restrict__ alpha)
{
    const int b = blockIdx.x >> 6, r = blockIdx.x & 63;
    const int s = threadIdx.x;
    const float* qr = q + ((size_t)b * R_ + r) * DK_;
    const float* ks = k + ((size_t)b * R_ + s) * DK_;
    float acc = 0.f;
#pragma unroll
    for (int d = 0; d < DK_; ++d) acc += qr[d] * ks[d];
    acc = acc * 0.125f + preS[((size_t)b * R_ + r) * R_ + s];
    float mx = acc;
#pragma unroll
    for (int o = 32; o > 0; o >>= 1) mx = fmaxf(mx, __shfl_xor(mx, o, 64));
    float e = __expf(acc - mx);
    float sm = e;
#pragma unroll
    for (int o = 32; o > 0; o >>= 1) sm += __shfl_xor(sm, o, 64);
    alpha[((size_t)b * R_ + r) * R_ + s] = e / sm;
}

// z_small = alpha @ v.  One block per (b,r).
__global__ __launch_bounds__(256) void attn_z(const float* __restrict__ alpha,
                                              const float* __restrict__ v,
                                              float* __restrict__ zs)
{
    const int b = blockIdx.x >> 6, r = blockIdx.x & 63;
    const int t = threadIdx.x;
    __shared__ float al[R_];
    if (t < R_) al[t] = alpha[((size_t)b * R_ + r) * R_ + t];
    __syncthreads();
    float acc[4] = {};
    for (int s = 0; s < R_; ++s) {
        float a = al[s];
        const float* vr = v + ((size_t)b * R_ + s) * H_;
#pragma unroll
        for (int j = 0; j < 4; ++j) acc[j] += a * vr[t + j * 256];
    }
#pragma unroll
    for (int j = 0; j < 4; ++j) zs[((size_t)b * R_ + r) * H_ + t + j * 256] = acc[j];
}

// Row layernorm over C=512 of bf16 y, write fp32 out.
__global__ __launch_bounds__(256) void layernorm(const __hip_bfloat16* __restrict__ y,
                                                 const float* __restrict__ gamma,
                                                 const float* __restrict__ beta,
                                                 float* __restrict__ out)
{
    const size_t m = blockIdx.x;
    const int t = threadIdx.x;
    const __hip_bfloat16* yr = y + m * C_;
    float v0 = __bfloat162float(yr[t]), v1 = __bfloat162float(yr[t + 256]);
    __shared__ float rs[256], rq[256];
    rs[t] = v0 + v1;
    rq[t] = v0 * v0 + v1 * v1;
    __syncthreads();
    for (int o = 128; o > 0; o >>= 1) {
        if (t < o) { rs[t] += rs[t + o]; rq[t] += rq[t + o]; }
        __syncthreads();
    }
    const float mu = rs[0] * (1.0f / C_);
    const float var = rq[0] * (1.0f / C_) - mu * mu;
    const float inv = rsqrtf(var + 1e-5f);
    out[m * C_ + t] = (v0 - mu) * inv * gamma[t] + beta[t];
    out[m * C_ + t + 256] = (v1 - mu) * inv * gamma[t + 256] + beta[t + 256];
}

extern "C" void kernel_launch(void* const* d_in, const int* in_sizes, int n_in,
                              void* d_out, int out_size, void* d_ws, size_t ws_size,
                              hipStream_t stream)
{
    using bf16 = __hip_bfloat16;
    const float* x      = (const float*)d_in[0];
    const int*  maskPAD = (const int*)d_in[1];
    const float* preS   = (const float*)d_in[2];
    const float* Wp     = (const float*)d_in[3];
    const float* bp     = (const float*)d_in[4];
    const float* Wq     = (const float*)d_in[5];
    const float* bq     = (const float*)d_in[6];
    const float* Wk     = (const float*)d_in[7];
    const float* bk     = (const float*)d_in[8];
    const float* Wv     = (const float*)d_in[9];
    const float* bv     = (const float*)d_in[10];
    const float* Wu     = (const float*)d_in[11];
    const float* bu     = (const float*)d_in[12];
    const float* Wo     = (const float*)d_in[13];
    const float* bo     = (const float*)d_in[14];
    const float* gamma  = (const float*)d_in[15];
    const float* beta   = (const float*)d_in[16];
    float* out          = (float*)d_out;

    char* ws = (char*)d_ws;

    // ws_size is constant for the session, so this branch is graph-stable.
    const bool bigWS = ws_size >= (size_t)52 * 1024 * 1024;  // full plan needs 51.8 MB

    if (bigWS) {
        // ---- Full-M plan (11 launches), needs ~49.4 MiB ----
        bf16* gate = (bf16*)ws;                                 // M*H bf16
        char* pool = ws + (size_t)M_ * H_ * 2;
        float* pScore = (float*)pool;
        float* pAL   = pScore + (size_t)M_ * R_;
        float* pAR   = pAL    + (size_t)M_ * R_;
        float* px    = pAR    + (size_t)M_ * R_;
        float* q     = px     + (size_t)B_ * R_ * C_;
        float* kk    = q      + (size_t)B_ * R_ * DK_;
        float* vv    = kk     + (size_t)B_ * R_ * DK_;
        float* alpha = vv     + (size_t)B_ * R_ * H_;
        float* zs    = alpha  + (size_t)B_ * R_ * R_;
        bf16* y      = (bf16*)pool;   // aliases dead pool at k10

        gemm64<float, float, float, 1, 0><<<dim3(H_ / 64, M_ / 64), 256, 0, stream>>>(
            x, Wu, bu, nullptr, (const float*)nullptr, nullptr, gate, H_, C_, 0);
        gemm64<float, float, float, 0, 1><<<dim3(R_ / 64, M_ / 64), 256, 0, stream>>>(
            x, Wp, bp, maskPAD, (const float*)nullptr, pScore, nullptr, R_, C_, 0);
        softmaxL<<<B_ * R_, 256, 0, stream>>>(pScore, pAL);
        softmaxR<<<M_, 64, 0, stream>>>(pScore, pAR);
        compress<<<B_ * R_, 256, 0, stream>>>(pAL, x, px);
        qkv<<<B_ * R_, 256, 0, stream>>>(px, Wq, bq, Wk, bk, Wv, bv, q, kk, vv);
        attn_scores<<<B_ * R_, 64, 0, stream>>>(q, kk, preS, alpha);
        attn_z<<<B_ * R_, 256, 0, stream>>>(alpha, vv, zs);
        gemm64<float, float, bf16, 0, 3><<<dim3(H_ / 64, M_ / 64), 256, 0, stream>>>(
            pAR, zs, nullptr, nullptr, gate, nullptr, gate, H_, R_, (long)R_ * H_);
        gemm64<bf16, float, float, 0, 2><<<dim3(C_ / 64, M_ / 64), 256, 0, stream>>>(
            gate, Wo, bo, nullptr, x, nullptr, y, C_, H_, 0);
        layernorm<<<M_, 256, 0, stream>>>(y, gamma, beta, out);
    } else {
        // ---- Compact plan (~23.4 MiB): per-batch [.,H] stages ----
        float* pScore = (float*)ws;                             // M*R
        float* pAL   = pScore + (size_t)M_ * R_;
        float* pAR   = pAL    + (size_t)M_ * R_;
        float* px    = pAR    + (size_t)M_ * R_;
        float* q     = px     + (size_t)B_ * R_ * C_;
        float* kk    = q      + (size_t)B_ * R_ * DK_;
        float* vv    = kk     + (size_t)B_ * R_ * DK_;
        float* alpha = vv     + (size_t)B_ * R_ * H_;
        float* zs    = alpha  + (size_t)B_ * R_ * R_;
        bf16* gate_b = (bf16*)(zs + (size_t)B_ * R_ * H_);      // L*H bf16 (reused)
        bf16* y_b    = (bf16*)((char*)gate_b + (size_t)L_ * H_ * 2);  // L*C bf16

        gemm64<float, float, float, 0, 1><<<dim3(R_ / 64, M_ / 64), 256, 0, stream>>>(
            x, Wp, bp, maskPAD, (const float*)nullptr, pScore, nullptr, R_, C_, 0);
        softmaxL<<<B_ * R_, 256, 0, stream>>>(pScore, pAL);
        softmaxR<<<M_, 64, 0, stream>>>(pScore, pAR);
        compress<<<B_ * R_, 256, 0, stream>>>(pAL, x, px);
        qkv<<<B_ * R_, 256, 0, stream>>>(px, Wq, bq, Wk, bk, Wv, bv, q, kk, vv);
        attn_scores<<<B_ * R_, 64, 0, stream>>>(q, kk, preS, alpha);
        attn_z<<<B_ * R_, 256, 0, stream>>>(alpha, vv, zs);

        for (int b = 0; b < B_; ++b) {
            const float* xb = x + (size_t)b * L_ * C_;
            // gate_b = silu(xb @ Wu + bu)   [L,H] bf16
            gemm64<float, float, float, 1, 0><<<dim3(H_ / 64, L_ / 64), 256, 0, stream>>>(
                xb, Wu, bu, nullptr, (const float*)nullptr, nullptr, gate_b, H_, C_, 0);
            // zg_b = gate_b * (pAR_b @ zs_b)   (in-place over gate_b)
            gemm64<float, float, bf16, 0, 3><<<dim3(H_ / 64, L_ / 64), 256, 0, stream>>>(
                pAR + (size_t)b * L_ * R_, zs + (size_t)b * R_ * H_,
                nullptr, nullptr, gate_b, nullptr, gate_b, H_, R_, 0);
            // y_b = xb + zg_b @ Wo + bo   [L,C] bf16
            gemm64<bf16, float, float, 0, 2><<<dim3(C_ / 64, L_ / 64), 256, 0, stream>>>(
                gate_b, Wo, bo, nullptr, xb, nullptr, y_b, C_, H_, 0);
            // layernorm rows of this batch -> out
            layernorm<<<L_, 256, 0, stream>>>(y_b, gamma, beta, out + (size_t)b * L_ * C_);
        }
    }
}

// Round 4
// 756.856 us; speedup vs baseline: 1.5254x; 1.5254x over previous
//
#include <hip/hip_runtime.h>
#include <hip/hip_bf16.h>

// Problem constants
constexpr int B_ = 8;
constexpr int L_ = 2048;
constexpr int C_ = 512;
constexpr int R_ = 64;
constexpr int DK_ = 64;
constexpr int H_ = 1024;   // 2*C
constexpr int M_ = B_ * L_;  // 16384
constexpr float NEG_ = -32767.0f;

__device__ __forceinline__ float toF(float x) { return x; }
__device__ __forceinline__ float toF(__hip_bfloat16 x) { return __bfloat162float(x); }
__device__ __forceinline__ float siluf(float v) { return v / (1.0f + __expf(-v)); }

// ---------------------------------------------------------------------------
// Generic 64x64 tiled GEMM, BK=16, 256 threads, 4x4 micro-tile per thread.
// EPI: 0 = bias + silu -> bf16 out (gate)
//      1 = bias, apply maskPAD (row==0 -> NEG), store f32 (pScore)
//      2 = bias + residual (RT) -> bf16 out (pre-layernorm y)
//      3 = multiply by resid (RT, same buffer as outB, elementwise in-place)
// ---------------------------------------------------------------------------
template <typename AT, typename BT, typename RT, int ACT, int EPI>
__global__ __launch_bounds__(256) void gemm64(
    const AT* __restrict__ A, const BT* __restrict__ Bw,
    const float* __restrict__ bias,
    const int* __restrict__ mask,
    const RT* resid,
    float* __restrict__ outF, __hip_bfloat16* outB,
    int Ndim, int Kdim, long bBatchStride)
{
    __shared__ float As[16][68];   // transposed A tile: As[k][m]
    __shared__ float Bs[16][64];   // Bs[k][n]
    const int tid = threadIdx.x;
    const int tx = tid & 15, ty = tid >> 4;
    const int n0 = blockIdx.x * 64, m0 = blockIdx.y * 64;
    const BT* Bp = Bw + (bBatchStride ? (long)(m0 / L_) * bBatchStride : 0);

    float acc[4][4] = {};

    for (int k0 = 0; k0 < Kdim; k0 += 16) {
#pragma unroll
        for (int s = 0; s < 4; ++s) {
            int idx = tid + s * 256;          // 64x16 = 1024 elems
            int am = idx >> 4, ak = idx & 15;
            As[ak][am] = toF(A[(size_t)(m0 + am) * Kdim + k0 + ak]);
        }
#pragma unroll
        for (int s = 0; s < 4; ++s) {
            int idx = tid + s * 256;          // 16x64 = 1024 elems
            int bk = idx >> 6, bn = idx & 63;
            Bs[bk][bn] = toF(Bp[(size_t)(k0 + bk) * Ndim + n0 + bn]);
        }
        __syncthreads();
#pragma unroll
        for (int kk = 0; kk < 16; ++kk) {
            float av[4], bv[4];
            *(float4*)av = *(const float4*)&As[kk][ty * 4];
            *(float4*)bv = *(const float4*)&Bs[kk][tx * 4];
#pragma unroll
            for (int i = 0; i < 4; ++i)
#pragma unroll
                for (int j = 0; j < 4; ++j) acc[i][j] += av[i] * bv[j];
        }
        __syncthreads();
    }

#pragma unroll
    for (int i = 0; i < 4; ++i) {
        int m = m0 + ty * 4 + i;
#pragma unroll
        for (int j = 0; j < 4; ++j) {
            int n = n0 + tx * 4 + j;
            float val = acc[i][j];
            if (EPI != 3) val += bias[n];
            if (ACT) val = siluf(val);
            if (EPI == 0) {
                outB[(size_t)m * Ndim + n] = __float2bfloat16(val);
            } else if (EPI == 1) {
                if (mask[m] == 0) val = NEG_;
                outF[(size_t)m * Ndim + n] = val;
            } else if (EPI == 2) {
                val += toF(resid[(size_t)m * Ndim + n]);
                outB[(size_t)m * Ndim + n] = __float2bfloat16(val);
            } else {
                val *= toF(resid[(size_t)m * Ndim + n]);
                outB[(size_t)m * Ndim + n] = __float2bfloat16(val);
            }
        }
    }
}

// softmax over L (axis=1). One block per (b, r). pScore strided by R.
__global__ __launch_bounds__(256) void softmaxL(const float* __restrict__ pScore,
                                                float* __restrict__ pAlpha)
{
    const int b = blockIdx.x >> 6, r = blockIdx.x & 63;
    const int t = threadIdx.x;
    const float* base = pScore + (size_t)b * L_ * R_ + r;
    float* out = pAlpha + (size_t)b * L_ * R_ + r;
    __shared__ float red[256];

    float mx = -3.4e38f;
    for (int l = t; l < L_; l += 256) mx = fmaxf(mx, base[(size_t)l * R_]);
    red[t] = mx; __syncthreads();
    for (int s = 128; s > 0; s >>= 1) { if (t < s) red[t] = fmaxf(red[t], red[t + s]); __syncthreads(); }
    mx = red[0]; __syncthreads();

    float sum = 0.f;
    for (int l = t; l < L_; l += 256) {
        float e = __expf(base[(size_t)l * R_] - mx);
        out[(size_t)l * R_] = e;
        sum += e;
    }
    red[t] = sum; __syncthreads();
    for (int s = 128; s > 0; s >>= 1) { if (t < s) red[t] += red[t + s]; __syncthreads(); }
    const float inv = 1.0f / red[0];
    for (int l = t; l < L_; l += 256) out[(size_t)l * R_] *= inv;
}

// softmax over r (axis=-1). One 64-thread wave per row m.
__global__ __launch_bounds__(64) void softmaxR(const float* __restrict__ pScore,
                                               float* __restrict__ pAlphaR)
{
    const size_t m = blockIdx.x;
    const int t = threadIdx.x;
    float v = pScore[m * R_ + t];
    float mx = v;
#pragma unroll
    for (int o = 32; o > 0; o >>= 1) mx = fmaxf(mx, __shfl_xor(mx, o, 64));
    float e = __expf(v - mx);
    float s = e;
#pragma unroll
    for (int o = 32; o > 0; o >>= 1) s += __shfl_xor(s, o, 64);
    pAlphaR[m * R_ + t] = e / s;
}

// ---------------------------------------------------------------------------
// compress as K-split GEMM: parts[ks][b][r][c] = sum_{l in chunk ks} pAL[b][l][r]*x[b][l][c]
// pAL is already K-major for the A^T operand (l=k, r=m) -> all loads coalesced.
// grid (C/64, 4, B), 256 threads, 64x64 tile, BK=16.
// ---------------------------------------------------------------------------
__global__ __launch_bounds__(256) void compress_part(
    const float* __restrict__ pAlpha, const float* __restrict__ x,
    float* __restrict__ parts)
{
    __shared__ float As[16][64];
    __shared__ float Bs[16][64];
    const int tid = threadIdx.x;
    const int tx = tid & 15, ty = tid >> 4;
    const int n0 = blockIdx.x * 64;
    const int ks = blockIdx.y;
    const int b  = blockIdx.z;
    const float* pa = pAlpha + (size_t)b * L_ * R_;
    const float* xb = x + (size_t)b * L_ * C_;
    float acc[4][4] = {};
    const int kbeg = ks * (L_ / 4), kend = kbeg + L_ / 4;
    for (int k0 = kbeg; k0 < kend; k0 += 16) {
#pragma unroll
        for (int s = 0; s < 4; ++s) {
            int idx = tid + s * 256;
            int kk = idx >> 6, m = idx & 63;
            As[kk][m] = pa[(size_t)(k0 + kk) * R_ + m];
        }
#pragma unroll
        for (int s = 0; s < 4; ++s) {
            int idx = tid + s * 256;
            int kk = idx >> 6, n = idx & 63;
            Bs[kk][n] = xb[(size_t)(k0 + kk) * C_ + n0 + n];
        }
        __syncthreads();
#pragma unroll
        for (int kk = 0; kk < 16; ++kk) {
            float av[4], bv[4];
            *(float4*)av = *(const float4*)&As[kk][ty * 4];
            *(float4*)bv = *(const float4*)&Bs[kk][tx * 4];
#pragma unroll
            for (int i = 0; i < 4; ++i)
#pragma unroll
                for (int j = 0; j < 4; ++j) acc[i][j] += av[i] * bv[j];
        }
        __syncthreads();
    }
#pragma unroll
    for (int i = 0; i < 4; ++i)
#pragma unroll
        for (int j = 0; j < 4; ++j)
            parts[((((size_t)ks * B_ + b) * R_) + ty * 4 + i) * C_ + n0 + tx * 4 + j] = acc[i][j];
}

__global__ __launch_bounds__(256) void compress_reduce(const float* __restrict__ parts,
                                                       float* __restrict__ px)
{
    const size_t i = (size_t)blockIdx.x * 256 + threadIdx.x;   // B*R*C = 262144
    constexpr size_t S = (size_t)B_ * R_ * C_;
    px[i] = parts[i] + parts[i + S] + parts[i + 2 * S] + parts[i + 3 * S];
}

// ---------------------------------------------------------------------------
// qkv as one fused-N GEMM: [512 x (64|64|1024) x 512], silu epilogue, f32 out.
// grid (18, 8): bx==0 -> Wq, bx==1 -> Wk, bx>=2 -> Wv tile (bx-2).
// ---------------------------------------------------------------------------
__global__ __launch_bounds__(256) void qkv_gemm(
    const float* __restrict__ px,
    const float* __restrict__ Wq, const float* __restrict__ bq,
    const float* __restrict__ Wk, const float* __restrict__ bk,
    const float* __restrict__ Wv, const float* __restrict__ bv,
    float* __restrict__ q, float* __restrict__ k, float* __restrict__ v)
{
    __shared__ float As[16][68];
    __shared__ float Bs[16][64];
    const int tid = threadIdx.x;
    const int tx = tid & 15, ty = tid >> 4;
    const int bx = blockIdx.x;
    const int m0 = blockIdx.y * 64;
    const float* W; const float* bias; float* dst; int Nloc, ncol0;
    if (bx == 0)      { W = Wq; bias = bq; dst = q; Nloc = 64;   ncol0 = 0; }
    else if (bx == 1) { W = Wk; bias = bk; dst = k; Nloc = 64;   ncol0 = 0; }
    else              { W = Wv; bias = bv; dst = v; Nloc = H_;   ncol0 = (bx - 2) * 64; }

    float acc[4][4] = {};
    for (int k0 = 0; k0 < C_; k0 += 16) {
#pragma unroll
        for (int s = 0; s < 4; ++s) {
            int idx = tid + s * 256;
            int am = idx >> 4, ak = idx & 15;
            As[ak][am] = px[(size_t)(m0 + am) * C_ + k0 + ak];
        }
#pragma unroll
        for (int s = 0; s < 4; ++s) {
            int idx = tid + s * 256;
            int kk = idx >> 6, bn = idx & 63;
            Bs[kk][bn] = W[(size_t)(k0 + kk) * Nloc + ncol0 + bn];
        }
        __syncthreads();
#pragma unroll
        for (int kk = 0; kk < 16; ++kk) {
            float av[4], bv4[4];
            *(float4*)av = *(const float4*)&As[kk][ty * 4];
            *(float4*)bv4 = *(const float4*)&Bs[kk][tx * 4];
#pragma unroll
            for (int i = 0; i < 4; ++i)
#pragma unroll
                for (int j = 0; j < 4; ++j) acc[i][j] += av[i] * bv4[j];
        }
        __syncthreads();
    }
#pragma unroll
    for (int i = 0; i < 4; ++i) {
        int m = m0 + ty * 4 + i;
#pragma unroll
        for (int j = 0; j < 4; ++j) {
            int n = ncol0 + tx * 4 + j;
            dst[(size_t)m * Nloc + n] = siluf(acc[i][j] + bias[n]);
        }
    }
}

// scores + softmax -> alpha.  One 64-thread wave per (b,r); lane = s.
__global__ __launch_bounds__(64) void attn_scores(
    const float* __restrict__ q, const float* __restrict__ k,
    const float* __restrict__ preS, float* __restrict__ alpha)
{
    const int b = blockIdx.x >> 6, r = blockIdx.x & 63;
    const int s = threadIdx.x;
    const float* qr = q + ((size_t)b * R_ + r) * DK_;
    const float* ks = k + ((size_t)b * R_ + s) * DK_;
    float acc = 0.f;
#pragma unroll
    for (int d = 0; d < DK_; ++d) acc += qr[d] * ks[d];
    acc = acc * 0.125f + preS[((size_t)b * R_ + r) * R_ + s];
    float mx = acc;
#pragma unroll
    for (int o = 32; o > 0; o >>= 1) mx = fmaxf(mx, __shfl_xor(mx, o, 64));
    float e = __expf(acc - mx);
    float sm = e;
#pragma unroll
    for (int o = 32; o > 0; o >>= 1) sm += __shfl_xor(sm, o, 64);
    alpha[((size_t)b * R_ + r) * R_ + s] = e / sm;
}

// z_small = alpha @ v.  One block per (b,r).
__global__ __launch_bounds__(256) void attn_z(const float* __restrict__ alpha,
                                              const float* __restrict__ v,
                                              float* __restrict__ zs)
{
    const int b = blockIdx.x >> 6, r = blockIdx.x & 63;
    const int t = threadIdx.x;
    __shared__ float al[R_];
    if (t < R_) al[t] = alpha[((size_t)b * R_ + r) * R_ + t];
    __syncthreads();
    float acc[4] = {};
    for (int s = 0; s < R_; ++s) {
        float a = al[s];
        const float* vr = v + ((size_t)b * R_ + s) * H_;
#pragma unroll
        for (int j = 0; j < 4; ++j) acc[j] += a * vr[t + j * 256];
    }
#pragma unroll
    for (int j = 0; j < 4; ++j) zs[((size_t)b * R_ + r) * H_ + t + j * 256] = acc[j];
}

// Row layernorm over C=512 of bf16 y, write fp32 out.
__global__ __launch_bounds__(256) void layernorm(const __hip_bfloat16* __restrict__ y,
                                                 const float* __restrict__ gamma,
                                                 const float* __restrict__ beta,
                                                 float* __restrict__ out)
{
    const size_t m = blockIdx.x;
    const int t = threadIdx.x;
    const __hip_bfloat16* yr = y + m * C_;
    float v0 = __bfloat162float(yr[t]), v1 = __bfloat162float(yr[t + 256]);
    __shared__ float rs[256], rq[256];
    rs[t] = v0 + v1;
    rq[t] = v0 * v0 + v1 * v1;
    __syncthreads();
    for (int o = 128; o > 0; o >>= 1) {
        if (t < o) { rs[t] += rs[t + o]; rq[t] += rq[t + o]; }
        __syncthreads();
    }
    const float mu = rs[0] * (1.0f / C_);
    const float var = rq[0] * (1.0f / C_) - mu * mu;
    const float inv = rsqrtf(var + 1e-5f);
    out[m * C_ + t] = (v0 - mu) * inv * gamma[t] + beta[t];
    out[m * C_ + t + 256] = (v1 - mu) * inv * gamma[t + 256] + beta[t + 256];
}

extern "C" void kernel_launch(void* const* d_in, const int* in_sizes, int n_in,
                              void* d_out, int out_size, void* d_ws, size_t ws_size,
                              hipStream_t stream)
{
    using bf16 = __hip_bfloat16;
    const float* x      = (const float*)d_in[0];
    const int*  maskPAD = (const int*)d_in[1];
    const float* preS   = (const float*)d_in[2];
    const float* Wp     = (const float*)d_in[3];
    const float* bp     = (const float*)d_in[4];
    const float* Wq     = (const float*)d_in[5];
    const float* bq     = (const float*)d_in[6];
    const float* Wk     = (const float*)d_in[7];
    const float* bk     = (const float*)d_in[8];
    const float* Wv     = (const float*)d_in[9];
    const float* bv     = (const float*)d_in[10];
    const float* Wu     = (const float*)d_in[11];
    const float* bu     = (const float*)d_in[12];
    const float* Wo     = (const float*)d_in[13];
    const float* bo     = (const float*)d_in[14];
    const float* gamma  = (const float*)d_in[15];
    const float* beta   = (const float*)d_in[16];
    float* out          = (float*)d_out;

    char* ws = (char*)d_ws;

    // ws_size is constant for the session, so this branch is graph-stable.
    const bool bigWS = ws_size >= (size_t)52 * 1024 * 1024;  // full plan needs 51.8 MB

    if (bigWS) {
        // ---- Full-M plan, needs ~49.4 MiB ----
        bf16* gate = (bf16*)ws;                                 // M*H bf16
        char* pool = ws + (size_t)M_ * H_ * 2;
        float* pScore = (float*)pool;                           // also reused as compress parts
        float* pAL   = pScore + (size_t)M_ * R_;
        float* pAR   = pAL    + (size_t)M_ * R_;
        float* px    = pAR    + (size_t)M_ * R_;
        float* q     = px     + (size_t)B_ * R_ * C_;
        float* kk    = q      + (size_t)B_ * R_ * DK_;
        float* vv    = kk     + (size_t)B_ * R_ * DK_;
        float* alpha = vv     + (size_t)B_ * R_ * H_;
        float* zs    = alpha  + (size_t)B_ * R_ * R_;
        bf16* y      = (bf16*)pool;   // aliases dead pool at k10

        gemm64<float, float, float, 1, 0><<<dim3(H_ / 64, M_ / 64), 256, 0, stream>>>(
            x, Wu, bu, nullptr, (const float*)nullptr, nullptr, gate, H_, C_, 0);
        gemm64<float, float, float, 0, 1><<<dim3(R_ / 64, M_ / 64), 256, 0, stream>>>(
            x, Wp, bp, maskPAD, (const float*)nullptr, pScore, nullptr, R_, C_, 0);
        softmaxL<<<B_ * R_, 256, 0, stream>>>(pScore, pAL);
        softmaxR<<<M_, 64, 0, stream>>>(pScore, pAR);
        // compress (pScore is dead now; reuse it as the 4 MB parts buffer)
        compress_part<<<dim3(C_ / 64, 4, B_), 256, 0, stream>>>(pAL, x, pScore);
        compress_reduce<<<(B_ * R_ * C_) / 256, 256, 0, stream>>>(pScore, px);
        qkv_gemm<<<dim3(2 + H_ / 64, (B_ * R_) / 64), 256, 0, stream>>>(
            px, Wq, bq, Wk, bk, Wv, bv, q, kk, vv);
        attn_scores<<<B_ * R_, 64, 0, stream>>>(q, kk, preS, alpha);
        attn_z<<<B_ * R_, 256, 0, stream>>>(alpha, vv, zs);
        gemm64<float, float, bf16, 0, 3><<<dim3(H_ / 64, M_ / 64), 256, 0, stream>>>(
            pAR, zs, nullptr, nullptr, gate, nullptr, gate, H_, R_, (long)R_ * H_);
        gemm64<bf16, float, float, 0, 2><<<dim3(C_ / 64, M_ / 64), 256, 0, stream>>>(
            gate, Wo, bo, nullptr, x, nullptr, y, C_, H_, 0);
        layernorm<<<M_, 256, 0, stream>>>(y, gamma, beta, out);
    } else {
        // ---- Compact plan (~23.4 MiB): per-batch [.,H] stages ----
        float* pScore = (float*)ws;                             // M*R; reused as compress parts
        float* pAL   = pScore + (size_t)M_ * R_;
        float* pAR   = pAL    + (size_t)M_ * R_;
        float* px    = pAR    + (size_t)M_ * R_;
        float* q     = px     + (size_t)B_ * R_ * C_;
        float* kk    = q      + (size_t)B_ * R_ * DK_;
        float* vv    = kk     + (size_t)B_ * R_ * DK_;
        float* alpha = vv     + (size_t)B_ * R_ * H_;
        float* zs    = alpha  + (size_t)B_ * R_ * R_;
        bf16* gate_b = (bf16*)(zs + (size_t)B_ * R_ * H_);      // L*H bf16 (reused)
        bf16* y_b    = (bf16*)((char*)gate_b + (size_t)L_ * H_ * 2);  // L*C bf16

        gemm64<float, float, float, 0, 1><<<dim3(R_ / 64, M_ / 64), 256, 0, stream>>>(
            x, Wp, bp, maskPAD, (const float*)nullptr, pScore, nullptr, R_, C_, 0);
        softmaxL<<<B_ * R_, 256, 0, stream>>>(pScore, pAL);
        softmaxR<<<M_, 64, 0, stream>>>(pScore, pAR);
        compress_part<<<dim3(C_ / 64, 4, B_), 256, 0, stream>>>(pAL, x, pScore);
        compress_reduce<<<(B_ * R_ * C_) / 256, 256, 0, stream>>>(pScore, px);
        qkv_gemm<<<dim3(2 + H_ / 64, (B_ * R_) / 64), 256, 0, stream>>>(
            px, Wq, bq, Wk, bk, Wv, bv, q, kk, vv);
        attn_scores<<<B_ * R_, 64, 0, stream>>>(q, kk, preS, alpha);
        attn_z<<<B_ * R_, 256, 0, stream>>>(alpha, vv, zs);

        for (int b = 0; b < B_; ++b) {
            const float* xb = x + (size_t)b * L_ * C_;
            gemm64<float, float, float, 1, 0><<<dim3(H_ / 64, L_ / 64), 256, 0, stream>>>(
                xb, Wu, bu, nullptr, (const float*)nullptr, nullptr, gate_b, H_, C_, 0);
            gemm64<float, float, bf16, 0, 3><<<dim3(H_ / 64, L_ / 64), 256, 0, stream>>>(
                pAR + (size_t)b * L_ * R_, zs + (size_t)b * R_ * H_,
                nullptr, nullptr, gate_b, nullptr, gate_b, H_, R_, 0);
            gemm64<bf16, float, float, 0, 2><<<dim3(C_ / 64, L_ / 64), 256, 0, stream>>>(
                gate_b, Wo, bo, nullptr, xb, nullptr, y_b, C_, H_, 0);
            layernorm<<<L_, 256, 0, stream>>>(y_b, gamma, beta, out + (size_t)b * L_ * C_);
        }
    }
}

// Round 5
// 390.409 us; speedup vs baseline: 2.9573x; 1.9386x over previous
//
#include <hip/hip_runtime.h>
#include <hip/hip_bf16.h>

// Problem constants
constexpr int B_ = 8;
constexpr int L_ = 2048;
constexpr int C_ = 512;
constexpr int R_ = 64;
constexpr int DK_ = 64;
constexpr int H_ = 1024;   // 2*C
constexpr int M_ = B_ * L_;  // 16384
constexpr float NEG_ = -32767.0f;

__device__ __forceinline__ float toF(float x) { return x; }
__device__ __forceinline__ float toF(__hip_bfloat16 x) { return __bfloat162float(x); }
__device__ __forceinline__ float siluf(float v) { return v / (1.0f + __expf(-v)); }
__device__ __forceinline__ ushort bfbits(float f) {
    __hip_bfloat16 h = __float2bfloat16(f);
    union { __hip_bfloat16 h; ushort u; } cv; cv.h = h; return cv.u;
}

typedef __attribute__((ext_vector_type(8))) short bf16x8;   // 8 bf16 (4 VGPRs)
typedef __attribute__((ext_vector_type(4))) float f32x4;    // 4 fp32 acc

// ---------------------------------------------------------------------------
// MFMA bf16 GEMM: out[M,N](bf16) = epi(A[M,K](bf16) @ Bt[N,K](bf16)^T).
// 128x128 block tile, 4 waves (2x2 of 64x64 wave tiles), BK=32,
// mfma_f32_16x16x32_bf16, 4x4 subtiles/wave.
// EPI 0: val = silu(acc + bias[n])            -> bf16
// EPI 2: val = acc + bias[n] + resid[m][n]    -> bf16   (resid fp32)
// LDS rows padded to 40 bf16 (80 B, 16B-multiple): ds_read_b128 aligned,
// max 2-way bank aliasing (free, m136).
// ---------------------------------------------------------------------------
template <int EPI>
__global__ __launch_bounds__(256) void mfma_gemm(
    const ushort* __restrict__ A, const ushort* __restrict__ Bt,
    const float* __restrict__ bias, const float* __restrict__ resid,
    ushort* __restrict__ out, int Ndim, int Kdim)
{
    constexpr int LDA = 40;
    __shared__ ushort As[128 * LDA];
    __shared__ ushort Bs[128 * LDA];
    const int tid = threadIdx.x;
    const int lane = tid & 63, w = tid >> 6;
    const int wm = (w & 1) * 64, wn = (w >> 1) * 64;
    const int m0 = blockIdx.y * 128, n0 = blockIdx.x * 128;
    const int lr = lane & 15, lq = lane >> 4;
    const int srow = tid >> 2, scol = (tid & 3) * 8;   // staging: 64 rows x 32 k / pass

    f32x4 acc[4][4];
#pragma unroll
    for (int i = 0; i < 4; ++i)
#pragma unroll
        for (int j = 0; j < 4; ++j) acc[i][j] = (f32x4){0.f, 0.f, 0.f, 0.f};

    for (int k0 = 0; k0 < Kdim; k0 += 32) {
        const uint4 a0 = *(const uint4*)(A + (size_t)(m0 + srow) * Kdim + k0 + scol);
        const uint4 a1 = *(const uint4*)(A + (size_t)(m0 + 64 + srow) * Kdim + k0 + scol);
        const uint4 b0 = *(const uint4*)(Bt + (size_t)(n0 + srow) * Kdim + k0 + scol);
        const uint4 b1 = *(const uint4*)(Bt + (size_t)(n0 + 64 + srow) * Kdim + k0 + scol);
        __syncthreads();   // previous iteration's LDS reads done
        *(uint4*)&As[srow * LDA + scol] = a0;
        *(uint4*)&As[(64 + srow) * LDA + scol] = a1;
        *(uint4*)&Bs[srow * LDA + scol] = b0;
        *(uint4*)&Bs[(64 + srow) * LDA + scol] = b1;
        __syncthreads();

        bf16x8 af[4], bfr[4];
#pragma unroll
        for (int i = 0; i < 4; ++i)
            af[i] = *(const bf16x8*)&As[(wm + i * 16 + lr) * LDA + lq * 8];
#pragma unroll
        for (int j = 0; j < 4; ++j)
            bfr[j] = *(const bf16x8*)&Bs[(wn + j * 16 + lr) * LDA + lq * 8];
#pragma unroll
        for (int i = 0; i < 4; ++i)
#pragma unroll
            for (int j = 0; j < 4; ++j)
                acc[i][j] = __builtin_amdgcn_mfma_f32_16x16x32_bf16(af[i], bfr[j], acc[i][j], 0, 0, 0);
    }

#pragma unroll
    for (int i = 0; i < 4; ++i) {
#pragma unroll
        for (int j = 0; j < 4; ++j) {
            const int col = n0 + wn + j * 16 + lr;
            const float bn = bias[col];
#pragma unroll
            for (int r = 0; r < 4; ++r) {
                const int row = m0 + wm + i * 16 + lq * 4 + r;
                float v = acc[i][j][r] + bn;
                if (EPI == 0) v = siluf(v);
                else          v += resid[(size_t)row * Ndim + col];
                out[(size_t)row * Ndim + col] = bfbits(v);
            }
        }
    }
}

// x fp32 -> bf16, 4 elems/thread
__global__ __launch_bounds__(256) void f32_to_bf16_k(const float* __restrict__ in,
                                                     ushort* __restrict__ out)
{
    const size_t i = ((size_t)blockIdx.x * 256 + threadIdx.x) * 4;
    const float4 v = *(const float4*)(in + i);
    ushort4 o;
    o.x = bfbits(v.x); o.y = bfbits(v.y); o.z = bfbits(v.z); o.w = bfbits(v.w);
    *(ushort4*)(out + i) = o;
}

// W[K,N] fp32 -> Wt[N,K] bf16 (32x32 LDS tiles)
__global__ __launch_bounds__(256) void transpose_to_bf16(
    const float* __restrict__ W, ushort* __restrict__ Wt, int K, int N)
{
    __shared__ float tile[32][33];
    const int tx = threadIdx.x & 31, ty = threadIdx.x >> 5;   // 32x8
    const int n0 = blockIdx.x * 32, k0 = blockIdx.y * 32;
#pragma unroll
    for (int i = 0; i < 32; i += 8)
        tile[ty + i][tx] = W[(size_t)(k0 + ty + i) * N + n0 + tx];
    __syncthreads();
#pragma unroll
    for (int i = 0; i < 32; i += 8)
        Wt[(size_t)(n0 + ty + i) * K + k0 + tx] = bfbits(tile[tx][ty + i]);
}

// ---------------------------------------------------------------------------
// SIMT 64x64 tiled GEMM (kept for pScore / expand / compact path).
// ---------------------------------------------------------------------------
template <typename AT, typename BT, typename RT, int ACT, int EPI>
__global__ __launch_bounds__(256) void gemm64(
    const AT* __restrict__ A, const BT* __restrict__ Bw,
    const float* __restrict__ bias,
    const int* __restrict__ mask,
    const RT* resid,
    float* __restrict__ outF, __hip_bfloat16* outB,
    int Ndim, int Kdim, long bBatchStride)
{
    __shared__ float As[16][68];
    __shared__ float Bs[16][64];
    const int tid = threadIdx.x;
    const int tx = tid & 15, ty = tid >> 4;
    const int n0 = blockIdx.x * 64, m0 = blockIdx.y * 64;
    const BT* Bp = Bw + (bBatchStride ? (long)(m0 / L_) * bBatchStride : 0);

    float acc[4][4] = {};

    for (int k0 = 0; k0 < Kdim; k0 += 16) {
#pragma unroll
        for (int s = 0; s < 4; ++s) {
            int idx = tid + s * 256;
            int am = idx >> 4, ak = idx & 15;
            As[ak][am] = toF(A[(size_t)(m0 + am) * Kdim + k0 + ak]);
        }
#pragma unroll
        for (int s = 0; s < 4; ++s) {
            int idx = tid + s * 256;
            int bk = idx >> 6, bn = idx & 63;
            Bs[bk][bn] = toF(Bp[(size_t)(k0 + bk) * Ndim + n0 + bn]);
        }
        __syncthreads();
#pragma unroll
        for (int kk = 0; kk < 16; ++kk) {
            float av[4], bv[4];
            *(float4*)av = *(const float4*)&As[kk][ty * 4];
            *(float4*)bv = *(const float4*)&Bs[kk][tx * 4];
#pragma unroll
            for (int i = 0; i < 4; ++i)
#pragma unroll
                for (int j = 0; j < 4; ++j) acc[i][j] += av[i] * bv[j];
        }
        __syncthreads();
    }

#pragma unroll
    for (int i = 0; i < 4; ++i) {
        int m = m0 + ty * 4 + i;
#pragma unroll
        for (int j = 0; j < 4; ++j) {
            int n = n0 + tx * 4 + j;
            float val = acc[i][j];
            if (EPI != 3) val += bias[n];
            if (ACT) val = siluf(val);
            if (EPI == 0) {
                outB[(size_t)m * Ndim + n] = __float2bfloat16(val);
            } else if (EPI == 1) {
                if (mask[m] == 0) val = NEG_;
                outF[(size_t)m * Ndim + n] = val;
            } else if (EPI == 2) {
                val += toF(resid[(size_t)m * Ndim + n]);
                outB[(size_t)m * Ndim + n] = __float2bfloat16(val);
            } else {
                val *= toF(resid[(size_t)m * Ndim + n]);
                outB[(size_t)m * Ndim + n] = __float2bfloat16(val);
            }
        }
    }
}

// softmax over L (axis=1). One block per (b, r).
__global__ __launch_bounds__(256) void softmaxL(const float* __restrict__ pScore,
                                                float* __restrict__ pAlpha)
{
    const int b = blockIdx.x >> 6, r = blockIdx.x & 63;
    const int t = threadIdx.x;
    const float* base = pScore + (size_t)b * L_ * R_ + r;
    float* out = pAlpha + (size_t)b * L_ * R_ + r;
    __shared__ float red[256];

    float mx = -3.4e38f;
    for (int l = t; l < L_; l += 256) mx = fmaxf(mx, base[(size_t)l * R_]);
    red[t] = mx; __syncthreads();
    for (int s = 128; s > 0; s >>= 1) { if (t < s) red[t] = fmaxf(red[t], red[t + s]); __syncthreads(); }
    mx = red[0]; __syncthreads();

    float sum = 0.f;
    for (int l = t; l < L_; l += 256) {
        float e = __expf(base[(size_t)l * R_] - mx);
        out[(size_t)l * R_] = e;
        sum += e;
    }
    red[t] = sum; __syncthreads();
    for (int s = 128; s > 0; s >>= 1) { if (t < s) red[t] += red[t + s]; __syncthreads(); }
    const float inv = 1.0f / red[0];
    for (int l = t; l < L_; l += 256) out[(size_t)l * R_] *= inv;
}

// softmax over r (axis=-1). One wave per row m.
__global__ __launch_bounds__(64) void softmaxR(const float* __restrict__ pScore,
                                               float* __restrict__ pAlphaR)
{
    const size_t m = blockIdx.x;
    const int t = threadIdx.x;
    float v = pScore[m * R_ + t];
    float mx = v;
#pragma unroll
    for (int o = 32; o > 0; o >>= 1) mx = fmaxf(mx, __shfl_xor(mx, o, 64));
    float e = __expf(v - mx);
    float s = e;
#pragma unroll
    for (int o = 32; o > 0; o >>= 1) s += __shfl_xor(s, o, 64);
    pAlphaR[m * R_ + t] = e / s;
}

// compress K-split GEMM parts
__global__ __launch_bounds__(256) void compress_part(
    const float* __restrict__ pAlpha, const float* __restrict__ x,
    float* __restrict__ parts)
{
    __shared__ float As[16][64];
    __shared__ float Bs[16][64];
    const int tid = threadIdx.x;
    const int tx = tid & 15, ty = tid >> 4;
    const int n0 = blockIdx.x * 64;
    const int ks = blockIdx.y;
    const int b  = blockIdx.z;
    const float* pa = pAlpha + (size_t)b * L_ * R_;
    const float* xb = x + (size_t)b * L_ * C_;
    float acc[4][4] = {};
    const int kbeg = ks * (L_ / 4), kend = kbeg + L_ / 4;
    for (int k0 = kbeg; k0 < kend; k0 += 16) {
#pragma unroll
        for (int s = 0; s < 4; ++s) {
            int idx = tid + s * 256;
            int kk = idx >> 6, m = idx & 63;
            As[kk][m] = pa[(size_t)(k0 + kk) * R_ + m];
        }
#pragma unroll
        for (int s = 0; s < 4; ++s) {
            int idx = tid + s * 256;
            int kk = idx >> 6, n = idx & 63;
            Bs[kk][n] = xb[(size_t)(k0 + kk) * C_ + n0 + n];
        }
        __syncthreads();
#pragma unroll
        for (int kk = 0; kk < 16; ++kk) {
            float av[4], bv[4];
            *(float4*)av = *(const float4*)&As[kk][ty * 4];
            *(float4*)bv = *(const float4*)&Bs[kk][tx * 4];
#pragma unroll
            for (int i = 0; i < 4; ++i)
#pragma unroll
                for (int j = 0; j < 4; ++j) acc[i][j] += av[i] * bv[j];
        }
        __syncthreads();
    }
#pragma unroll
    for (int i = 0; i < 4; ++i)
#pragma unroll
        for (int j = 0; j < 4; ++j)
            parts[((((size_t)ks * B_ + b) * R_) + ty * 4 + i) * C_ + n0 + tx * 4 + j] = acc[i][j];
}

__global__ __launch_bounds__(256) void compress_reduce(const float* __restrict__ parts,
                                                       float* __restrict__ px)
{
    const size_t i = (size_t)blockIdx.x * 256 + threadIdx.x;
    constexpr size_t S = (size_t)B_ * R_ * C_;
    px[i] = parts[i] + parts[i + S] + parts[i + 2 * S] + parts[i + 3 * S];
}

// qkv fused-N GEMM
__global__ __launch_bounds__(256) void qkv_gemm(
    const float* __restrict__ px,
    const float* __restrict__ Wq, const float* __restrict__ bq,
    const float* __restrict__ Wk, const float* __restrict__ bk,
    const float* __restrict__ Wv, const float* __restrict__ bv,
    float* __restrict__ q, float* __restrict__ k, float* __restrict__ v)
{
    __shared__ float As[16][68];
    __shared__ float Bs[16][64];
    const int tid = threadIdx.x;
    const int tx = tid & 15, ty = tid >> 4;
    const int bx = blockIdx.x;
    const int m0 = blockIdx.y * 64;
    const float* W; const float* bias; float* dst; int Nloc, ncol0;
    if (bx == 0)      { W = Wq; bias = bq; dst = q; Nloc = 64;   ncol0 = 0; }
    else if (bx == 1) { W = Wk; bias = bk; dst = k; Nloc = 64;   ncol0 = 0; }
    else              { W = Wv; bias = bv; dst = v; Nloc = H_;   ncol0 = (bx - 2) * 64; }

    float acc[4][4] = {};
    for (int k0 = 0; k0 < C_; k0 += 16) {
#pragma unroll
        for (int s = 0; s < 4; ++s) {
            int idx = tid + s * 256;
            int am = idx >> 4, ak = idx & 15;
            As[ak][am] = px[(size_t)(m0 + am) * C_ + k0 + ak];
        }
#pragma unroll
        for (int s = 0; s < 4; ++s) {
            int idx = tid + s * 256;
            int kk = idx >> 6, bn = idx & 63;
            Bs[kk][bn] = W[(size_t)(k0 + kk) * Nloc + ncol0 + bn];
        }
        __syncthreads();
#pragma unroll
        for (int kk = 0; kk < 16; ++kk) {
            float av[4], bv4[4];
            *(float4*)av = *(const float4*)&As[kk][ty * 4];
            *(float4*)bv4 = *(const float4*)&Bs[kk][tx * 4];
#pragma unroll
            for (int i = 0; i < 4; ++i)
#pragma unroll
                for (int j = 0; j < 4; ++j) acc[i][j] += av[i] * bv4[j];
        }
        __syncthreads();
    }
#pragma unroll
    for (int i = 0; i < 4; ++i) {
        int m = m0 + ty * 4 + i;
#pragma unroll
        for (int j = 0; j < 4; ++j) {
            int n = ncol0 + tx * 4 + j;
            dst[(size_t)m * Nloc + n] = siluf(acc[i][j] + bias[n]);
        }
    }
}

// scores + softmax -> alpha
__global__ __launch_bounds__(64) void attn_scores(
    const float* __restrict__ q, const float* __restrict__ k,
    const float* __restrict__ preS, float* __restrict__ alpha)
{
    const int b = blockIdx.x >> 6, r = blockIdx.x & 63;
    const int s = threadIdx.x;
    const float* qr = q + ((size_t)b * R_ + r) * DK_;
    const float* ks = k + ((size_t)b * R_ + s) * DK_;
    float acc = 0.f;
#pragma unroll
    for (int d = 0; d < DK_; ++d) acc += qr[d] * ks[d];
    acc = acc * 0.125f + preS[((size_t)b * R_ + r) * R_ + s];
    float mx = acc;
#pragma unroll
    for (int o = 32; o > 0; o >>= 1) mx = fmaxf(mx, __shfl_xor(mx, o, 64));
    float e = __expf(acc - mx);
    float sm = e;
#pragma unroll
    for (int o = 32; o > 0; o >>= 1) sm += __shfl_xor(sm, o, 64);
    alpha[((size_t)b * R_ + r) * R_ + s] = e / sm;
}

// z_small = alpha @ v
__global__ __launch_bounds__(256) void attn_z(const float* __restrict__ alpha,
                                              const float* __restrict__ v,
                                              float* __restrict__ zs)
{
    const int b = blockIdx.x >> 6, r = blockIdx.x & 63;
    const int t = threadIdx.x;
    __shared__ float al[R_];
    if (t < R_) al[t] = alpha[((size_t)b * R_ + r) * R_ + t];
    __syncthreads();
    float acc[4] = {};
    for (int s = 0; s < R_; ++s) {
        float a = al[s];
        const float* vr = v + ((size_t)b * R_ + s) * H_;
#pragma unroll
        for (int j = 0; j < 4; ++j) acc[j] += a * vr[t + j * 256];
    }
#pragma unroll
    for (int j = 0; j < 4; ++j) zs[((size_t)b * R_ + r) * H_ + t + j * 256] = acc[j];
}

// Row layernorm of bf16 y -> fp32 out
__global__ __launch_bounds__(256) void layernorm(const __hip_bfloat16* __restrict__ y,
                                                 const float* __restrict__ gamma,
                                                 const float* __restrict__ beta,
                                                 float* __restrict__ out)
{
    const size_t m = blockIdx.x;
    const int t = threadIdx.x;
    const __hip_bfloat16* yr = y + m * C_;
    float v0 = __bfloat162float(yr[t]), v1 = __bfloat162float(yr[t + 256]);
    __shared__ float rs[256], rq[256];
    rs[t] = v0 + v1;
    rq[t] = v0 * v0 + v1 * v1;
    __syncthreads();
    for (int o = 128; o > 0; o >>= 1) {
        if (t < o) { rs[t] += rs[t + o]; rq[t] += rq[t + o]; }
        __syncthreads();
    }
    const float mu = rs[0] * (1.0f / C_);
    const float var = rq[0] * (1.0f / C_) - mu * mu;
    const float inv = rsqrtf(var + 1e-5f);
    out[m * C_ + t] = (v0 - mu) * inv * gamma[t] + beta[t];
    out[m * C_ + t + 256] = (v1 - mu) * inv * gamma[t + 256] + beta[t + 256];
}

extern "C" void kernel_launch(void* const* d_in, const int* in_sizes, int n_in,
                              void* d_out, int out_size, void* d_ws, size_t ws_size,
                              hipStream_t stream)
{
    using bf16 = __hip_bfloat16;
    const float* x      = (const float*)d_in[0];
    const int*  maskPAD = (const int*)d_in[1];
    const float* preS   = (const float*)d_in[2];
    const float* Wp     = (const float*)d_in[3];
    const float* bp     = (const float*)d_in[4];
    const float* Wq     = (const float*)d_in[5];
    const float* bq     = (const float*)d_in[6];
    const float* Wk     = (const float*)d_in[7];
    const float* bk     = (const float*)d_in[8];
    const float* Wv     = (const float*)d_in[9];
    const float* bv     = (const float*)d_in[10];
    const float* Wu     = (const float*)d_in[11];
    const float* bu     = (const float*)d_in[12];
    const float* Wo     = (const float*)d_in[13];
    const float* bo     = (const float*)d_in[14];
    const float* gamma  = (const float*)d_in[15];
    const float* beta   = (const float*)d_in[16];
    float* out          = (float*)d_out;

    char* ws = (char*)d_ws;
    const bool bigWS = ws_size >= (size_t)52 * 1024 * 1024;  // round-4 profile proves this is taken

    if (bigWS) {
        // ---- layout: gate 32 MB | pool 17.4 MB | Wut+Wot 2 MB  = 51.4 MiB ----
        bf16* gate = (bf16*)ws;                                 // M*H bf16 (zg in-place later)
        char* pool = ws + (size_t)M_ * H_ * 2;
        float* pScore = (float*)pool;                           // reused: compress parts
        float* pAL   = pScore + (size_t)M_ * R_;
        float* pAR   = pAL    + (size_t)M_ * R_;
        float* px    = pAR    + (size_t)M_ * R_;
        float* q     = px     + (size_t)B_ * R_ * C_;
        float* kk    = q      + (size_t)B_ * R_ * DK_;
        float* vv    = kk     + (size_t)B_ * R_ * DK_;
        float* alpha = vv     + (size_t)B_ * R_ * H_;
        float* zs    = alpha  + (size_t)B_ * R_ * R_;
        ushort* x16  = (ushort*)pool;                           // x bf16, dead before pScore write
        bf16*  y     = (bf16*)pool;                             // pre-LN y, aliases dead pool at k10
        ushort* Wut  = (ushort*)(pool + 18221568);              // [H, C] bf16
        ushort* Wot  = Wut + (size_t)C_ * H_;                   // [C, H] bf16

        // prep: x -> bf16 ; Wu,Wo -> transposed bf16
        f32_to_bf16_k<<<(M_ * C_) / 1024, 256, 0, stream>>>(x, x16);
        transpose_to_bf16<<<dim3(H_ / 32, C_ / 32), 256, 0, stream>>>(Wu, Wut, C_, H_);
        transpose_to_bf16<<<dim3(C_ / 32, H_ / 32), 256, 0, stream>>>(Wo, Wot, H_, C_);

        // 1) gate = silu(x @ Wu + bu)  [MFMA]
        mfma_gemm<0><<<dim3(H_ / 128, M_ / 128), 256, 0, stream>>>(
            x16, Wut, bu, nullptr, (ushort*)gate, H_, C_);
        // 2) pScore = x @ Wp + bp, mask  (overwrites x16 - dead)
        gemm64<float, float, float, 0, 1><<<dim3(R_ / 64, M_ / 64), 256, 0, stream>>>(
            x, Wp, bp, maskPAD, (const float*)nullptr, pScore, nullptr, R_, C_, 0);
        softmaxL<<<B_ * R_, 256, 0, stream>>>(pScore, pAL);
        softmaxR<<<M_, 64, 0, stream>>>(pScore, pAR);
        compress_part<<<dim3(C_ / 64, 4, B_), 256, 0, stream>>>(pAL, x, pScore);
        compress_reduce<<<(B_ * R_ * C_) / 256, 256, 0, stream>>>(pScore, px);
        qkv_gemm<<<dim3(2 + H_ / 64, (B_ * R_) / 64), 256, 0, stream>>>(
            px, Wq, bq, Wk, bk, Wv, bv, q, kk, vv);
        attn_scores<<<B_ * R_, 64, 0, stream>>>(q, kk, preS, alpha);
        attn_z<<<B_ * R_, 256, 0, stream>>>(alpha, vv, zs);
        // 9) zg = gate * (pAR @ zs)   (SIMT, in-place)
        gemm64<float, float, bf16, 0, 3><<<dim3(H_ / 64, M_ / 64), 256, 0, stream>>>(
            pAR, zs, nullptr, nullptr, gate, nullptr, gate, H_, R_, (long)R_ * H_);
        // 10) y = x + zg @ Wo + bo  [MFMA, fp32 residual]
        mfma_gemm<2><<<dim3(C_ / 128, M_ / 128), 256, 0, stream>>>(
            (ushort*)gate, Wot, bo, x, (ushort*)y, C_, H_);
        layernorm<<<M_, 256, 0, stream>>>(y, gamma, beta, out);
    } else {
        // ---- Compact plan (~23.4 MiB), SIMT per-batch (dead branch in practice) ----
        float* pScore = (float*)ws;
        float* pAL   = pScore + (size_t)M_ * R_;
        float* pAR   = pAL    + (size_t)M_ * R_;
        float* px    = pAR    + (size_t)M_ * R_;
        float* q     = px     + (size_t)B_ * R_ * C_;
        float* kk    = q      + (size_t)B_ * R_ * DK_;
        float* vv    = kk     + (size_t)B_ * R_ * DK_;
        float* alpha = vv     + (size_t)B_ * R_ * H_;
        float* zs    = alpha  + (size_t)B_ * R_ * R_;
        bf16* gate_b = (bf16*)(zs + (size_t)B_ * R_ * H_);
        bf16* y_b    = (bf16*)((char*)gate_b + (size_t)L_ * H_ * 2);

        gemm64<float, float, float, 0, 1><<<dim3(R_ / 64, M_ / 64), 256, 0, stream>>>(
            x, Wp, bp, maskPAD, (const float*)nullptr, pScore, nullptr, R_, C_, 0);
        softmaxL<<<B_ * R_, 256, 0, stream>>>(pScore, pAL);
        softmaxR<<<M_, 64, 0, stream>>>(pScore, pAR);
        compress_part<<<dim3(C_ / 64, 4, B_), 256, 0, stream>>>(pAL, x, pScore);
        compress_reduce<<<(B_ * R_ * C_) / 256, 256, 0, stream>>>(pScore, px);
        qkv_gemm<<<dim3(2 + H_ / 64, (B_ * R_) / 64), 256, 0, stream>>>(
            px, Wq, bq, Wk, bk, Wv, bv, q, kk, vv);
        attn_scores<<<B_ * R_, 64, 0, stream>>>(q, kk, preS, alpha);
        attn_z<<<B_ * R_, 256, 0, stream>>>(alpha, vv, zs);

        for (int b = 0; b < B_; ++b) {
            const float* xb = x + (size_t)b * L_ * C_;
            gemm64<float, float, float, 1, 0><<<dim3(H_ / 64, L_ / 64), 256, 0, stream>>>(
                xb, Wu, bu, nullptr, (const float*)nullptr, nullptr, gate_b, H_, C_, 0);
            gemm64<float, float, bf16, 0, 3><<<dim3(H_ / 64, L_ / 64), 256, 0, stream>>>(
                pAR + (size_t)b * L_ * R_, zs + (size_t)b * R_ * H_,
                nullptr, nullptr, gate_b, nullptr, gate_b, H_, R_, 0);
            gemm64<bf16, float, float, 0, 2><<<dim3(C_ / 64, L_ / 64), 256, 0, stream>>>(
                gate_b, Wo, bo, nullptr, xb, nullptr, y_b, C_, H_, 0);
            layernorm<<<L_, 256, 0, stream>>>(y_b, gamma, beta, out + (size_t)b * L_ * C_);
        }
    }
}

// Round 6
// 370.997 us; speedup vs baseline: 3.1120x; 1.0523x over previous
//
#include <hip/hip_runtime.h>
#include <hip/hip_bf16.h>

// Problem constants
constexpr int B_ = 8;
constexpr int L_ = 2048;
constexpr int C_ = 512;
constexpr int R_ = 64;
constexpr int DK_ = 64;
constexpr int H_ = 1024;   // 2*C
constexpr int M_ = B_ * L_;  // 16384
constexpr float NEG_ = -32767.0f;

__device__ __forceinline__ float toF(float x) { return x; }
__device__ __forceinline__ float toF(__hip_bfloat16 x) { return __bfloat162float(x); }
__device__ __forceinline__ float siluf(float v) { return v / (1.0f + __expf(-v)); }
__device__ __forceinline__ ushort bfbits(float f) {
    __hip_bfloat16 h = __float2bfloat16(f);
    union { __hip_bfloat16 h; ushort u; } cv; cv.h = h; return cv.u;
}
__device__ __forceinline__ float bf2f(ushort u) {
    union { uint u; float f; } cv; cv.u = (uint)u << 16; return cv.f;
}

typedef __attribute__((ext_vector_type(8))) short bf16x8;   // 8 bf16 (4 VGPRs)
typedef __attribute__((ext_vector_type(4))) float f32x4;    // 4 fp32 acc

// ---------------------------------------------------------------------------
// MFMA bf16 GEMM, 128x64 block tile (M x N), BK=32, 4 waves = 2x2 of 64x32
// wave tiles, mfma_f32_16x16x32_bf16, 4x2 subtiles/wave.
// 1-D grid with XCD-aware swizzle: block i -> xcd = i&7 (round-robin
// assumption, perf-only); per-XCD contiguous m-tiles, n fastest, so all
// N-blocks sharing an A-tile co-reside on one XCD's L2.
// EPI 0: silu(acc + bias[n])                      -> bf16
// EPI 2: acc + bias[n] + residF[m][n] (fp32)      -> bf16
// EPI 3: acc * residB[m][n] (bf16, in-place ok)   -> bf16   (no bias)
// bBatch: if nonzero, Bt += (m0/L_)*bBatch (batched B, expand GEMM).
// ---------------------------------------------------------------------------
template <int EPI>
__global__ __launch_bounds__(256) void mfma_gemm2(
    const ushort* __restrict__ A, const ushort* __restrict__ Bt,
    const float* __restrict__ bias,
    const float* __restrict__ residF, const ushort* __restrict__ residB,
    ushort* __restrict__ out, int Ndim, int Kdim, int gridN, long bBatch)
{
    constexpr int LDA = 40;
    __shared__ ushort As[128 * LDA];
    __shared__ ushort Bs[64 * LDA];

    // XCD swizzle
    const int i = blockIdx.x;
    const int G = gridDim.x >> 3;          // blocks per XCD (grid divisible by 8)
    const int gi = (i & 7) * G + (i >> 3);
    const int nt = gi % gridN, mt = gi / gridN;
    const int m0 = mt * 128, n0 = nt * 64;

    const int tid = threadIdx.x;
    const int lane = tid & 63, w = tid >> 6;
    const int wm = (w & 1) * 64, wn = (w >> 1) * 32;
    const int lr = lane & 15, lq = lane >> 4;
    const int rowA = tid >> 1, colA = (tid & 1) * 16;   // 128 x 32 staging
    const int rowB = tid >> 2, colB = (tid & 3) * 8;    // 64 x 32 staging

    const ushort* Bp = Bt + (bBatch ? (long)(m0 / L_) * bBatch : 0);

    f32x4 acc[4][2];
#pragma unroll
    for (int a = 0; a < 4; ++a)
#pragma unroll
        for (int b = 0; b < 2; ++b) acc[a][b] = (f32x4){0.f, 0.f, 0.f, 0.f};

    for (int k0 = 0; k0 < Kdim; k0 += 32) {
        const uint4 a0 = *(const uint4*)(A + (size_t)(m0 + rowA) * Kdim + k0 + colA);
        const uint4 a1 = *(const uint4*)(A + (size_t)(m0 + rowA) * Kdim + k0 + colA + 8);
        const uint4 b0 = *(const uint4*)(Bp + (size_t)(n0 + rowB) * Kdim + k0 + colB);
        __syncthreads();   // previous iteration's LDS reads done
        *(uint4*)&As[rowA * LDA + colA] = a0;
        *(uint4*)&As[rowA * LDA + colA + 8] = a1;
        *(uint4*)&Bs[rowB * LDA + colB] = b0;
        __syncthreads();

        bf16x8 af[4], bf[2];
#pragma unroll
        for (int a = 0; a < 4; ++a)
            af[a] = *(const bf16x8*)&As[(wm + a * 16 + lr) * LDA + lq * 8];
#pragma unroll
        for (int b = 0; b < 2; ++b)
            bf[b] = *(const bf16x8*)&Bs[(wn + b * 16 + lr) * LDA + lq * 8];
#pragma unroll
        for (int a = 0; a < 4; ++a)
#pragma unroll
            for (int b = 0; b < 2; ++b)
                acc[a][b] = __builtin_amdgcn_mfma_f32_16x16x32_bf16(af[a], bf[b], acc[a][b], 0, 0, 0);
    }

#pragma unroll
    for (int a = 0; a < 4; ++a) {
#pragma unroll
        for (int b = 0; b < 2; ++b) {
            const int col = n0 + wn + b * 16 + lr;
            float bn = 0.f;
            if (EPI != 3) bn = bias[col];
#pragma unroll
            for (int r = 0; r < 4; ++r) {
                const int row = m0 + wm + a * 16 + lq * 4 + r;
                float v = acc[a][b][r];
                if (EPI == 0) { v = siluf(v + bn); }
                else if (EPI == 2) { v += bn + residF[(size_t)row * Ndim + col]; }
                else { v *= bf2f(residB[(size_t)row * Ndim + col]); }
                out[(size_t)row * Ndim + col] = bfbits(v);
            }
        }
    }
}

// x fp32 -> bf16, 4 elems/thread
__global__ __launch_bounds__(256) void f32_to_bf16_k(const float* __restrict__ in,
                                                     ushort* __restrict__ out)
{
    const size_t i = ((size_t)blockIdx.x * 256 + threadIdx.x) * 4;
    const float4 v = *(const float4*)(in + i);
    ushort4 o;
    o.x = bfbits(v.x); o.y = bfbits(v.y); o.z = bfbits(v.z); o.w = bfbits(v.w);
    *(ushort4*)(out + i) = o;
}

// W[K,N] fp32 -> Wt[N,K] bf16 (32x32 LDS tiles)
__global__ __launch_bounds__(256) void transpose_to_bf16(
    const float* __restrict__ W, ushort* __restrict__ Wt, int K, int N)
{
    __shared__ float tile[32][33];
    const int tx = threadIdx.x & 31, ty = threadIdx.x >> 5;   // 32x8
    const int n0 = blockIdx.x * 32, k0 = blockIdx.y * 32;
#pragma unroll
    for (int i = 0; i < 32; i += 8)
        tile[ty + i][tx] = W[(size_t)(k0 + ty + i) * N + n0 + tx];
    __syncthreads();
#pragma unroll
    for (int i = 0; i < 32; i += 8)
        Wt[(size_t)(n0 + ty + i) * K + k0 + tx] = bfbits(tile[tx][ty + i]);
}

// ---------------------------------------------------------------------------
// SIMT 64x64 tiled GEMM (kept for pScore / compact path).
// ---------------------------------------------------------------------------
template <typename AT, typename BT, typename RT, int ACT, int EPI>
__global__ __launch_bounds__(256) void gemm64(
    const AT* __restrict__ A, const BT* __restrict__ Bw,
    const float* __restrict__ bias,
    const int* __restrict__ mask,
    const RT* resid,
    float* __restrict__ outF, __hip_bfloat16* outB,
    int Ndim, int Kdim, long bBatchStride)
{
    __shared__ float As[16][68];
    __shared__ float Bs[16][64];
    const int tid = threadIdx.x;
    const int tx = tid & 15, ty = tid >> 4;
    const int n0 = blockIdx.x * 64, m0 = blockIdx.y * 64;
    const BT* Bp = Bw + (bBatchStride ? (long)(m0 / L_) * bBatchStride : 0);

    float acc[4][4] = {};

    for (int k0 = 0; k0 < Kdim; k0 += 16) {
#pragma unroll
        for (int s = 0; s < 4; ++s) {
            int idx = tid + s * 256;
            int am = idx >> 4, ak = idx & 15;
            As[ak][am] = toF(A[(size_t)(m0 + am) * Kdim + k0 + ak]);
        }
#pragma unroll
        for (int s = 0; s < 4; ++s) {
            int idx = tid + s * 256;
            int bk = idx >> 6, bn = idx & 63;
            Bs[bk][bn] = toF(Bp[(size_t)(k0 + bk) * Ndim + n0 + bn]);
        }
        __syncthreads();
#pragma unroll
        for (int kk = 0; kk < 16; ++kk) {
            float av[4], bv[4];
            *(float4*)av = *(const float4*)&As[kk][ty * 4];
            *(float4*)bv = *(const float4*)&Bs[kk][tx * 4];
#pragma unroll
            for (int i = 0; i < 4; ++i)
#pragma unroll
                for (int j = 0; j < 4; ++j) acc[i][j] += av[i] * bv[j];
        }
        __syncthreads();
    }

#pragma unroll
    for (int i = 0; i < 4; ++i) {
        int m = m0 + ty * 4 + i;
#pragma unroll
        for (int j = 0; j < 4; ++j) {
            int n = n0 + tx * 4 + j;
            float val = acc[i][j];
            if (EPI != 3) val += bias[n];
            if (ACT) val = siluf(val);
            if (EPI == 0) {
                outB[(size_t)m * Ndim + n] = __float2bfloat16(val);
            } else if (EPI == 1) {
                if (mask[m] == 0) val = NEG_;
                outF[(size_t)m * Ndim + n] = val;
            } else if (EPI == 2) {
                val += toF(resid[(size_t)m * Ndim + n]);
                outB[(size_t)m * Ndim + n] = __float2bfloat16(val);
            } else {
                val *= toF(resid[(size_t)m * Ndim + n]);
                outB[(size_t)m * Ndim + n] = __float2bfloat16(val);
            }
        }
    }
}

// softmax over L (axis=1). One block per (b, r).
__global__ __launch_bounds__(256) void softmaxL(const float* __restrict__ pScore,
                                                float* __restrict__ pAlpha)
{
    const int b = blockIdx.x >> 6, r = blockIdx.x & 63;
    const int t = threadIdx.x;
    const float* base = pScore + (size_t)b * L_ * R_ + r;
    float* out = pAlpha + (size_t)b * L_ * R_ + r;
    __shared__ float red[256];

    float mx = -3.4e38f;
    for (int l = t; l < L_; l += 256) mx = fmaxf(mx, base[(size_t)l * R_]);
    red[t] = mx; __syncthreads();
    for (int s = 128; s > 0; s >>= 1) { if (t < s) red[t] = fmaxf(red[t], red[t + s]); __syncthreads(); }
    mx = red[0]; __syncthreads();

    float sum = 0.f;
    for (int l = t; l < L_; l += 256) {
        float e = __expf(base[(size_t)l * R_] - mx);
        out[(size_t)l * R_] = e;
        sum += e;
    }
    red[t] = sum; __syncthreads();
    for (int s = 128; s > 0; s >>= 1) { if (t < s) red[t] += red[t + s]; __syncthreads(); }
    const float inv = 1.0f / red[0];
    for (int l = t; l < L_; l += 256) out[(size_t)l * R_] *= inv;
}

// softmax over r (axis=-1). One wave per row m. OUT=0: fp32, OUT=1: bf16 bits.
template <int OUT>
__global__ __launch_bounds__(64) void softmaxR(const float* __restrict__ pScore,
                                               float* __restrict__ outF,
                                               ushort* __restrict__ outU)
{
    const size_t m = blockIdx.x;
    const int t = threadIdx.x;
    float v = pScore[m * R_ + t];
    float mx = v;
#pragma unroll
    for (int o = 32; o > 0; o >>= 1) mx = fmaxf(mx, __shfl_xor(mx, o, 64));
    float e = __expf(v - mx);
    float s = e;
#pragma unroll
    for (int o = 32; o > 0; o >>= 1) s += __shfl_xor(s, o, 64);
    if (OUT == 0) outF[m * R_ + t] = e / s;
    else          outU[m * R_ + t] = bfbits(e / s);
}

// compress K-split GEMM parts
__global__ __launch_bounds__(256) void compress_part(
    const float* __restrict__ pAlpha, const float* __restrict__ x,
    float* __restrict__ parts)
{
    __shared__ float As[16][64];
    __shared__ float Bs[16][64];
    const int tid = threadIdx.x;
    const int tx = tid & 15, ty = tid >> 4;
    const int n0 = blockIdx.x * 64;
    const int ks = blockIdx.y;
    const int b  = blockIdx.z;
    const float* pa = pAlpha + (size_t)b * L_ * R_;
    const float* xb = x + (size_t)b * L_ * C_;
    float acc[4][4] = {};
    const int kbeg = ks * (L_ / 4), kend = kbeg + L_ / 4;
    for (int k0 = kbeg; k0 < kend; k0 += 16) {
#pragma unroll
        for (int s = 0; s < 4; ++s) {
            int idx = tid + s * 256;
            int kk = idx >> 6, m = idx & 63;
            As[kk][m] = pa[(size_t)(k0 + kk) * R_ + m];
        }
#pragma unroll
        for (int s = 0; s < 4; ++s) {
            int idx = tid + s * 256;
            int kk = idx >> 6, n = idx & 63;
            Bs[kk][n] = xb[(size_t)(k0 + kk) * C_ + n0 + n];
        }
        __syncthreads();
#pragma unroll
        for (int kk = 0; kk < 16; ++kk) {
            float av[4], bv[4];
            *(float4*)av = *(const float4*)&As[kk][ty * 4];
            *(float4*)bv = *(const float4*)&Bs[kk][tx * 4];
#pragma unroll
            for (int i = 0; i < 4; ++i)
#pragma unroll
                for (int j = 0; j < 4; ++j) acc[i][j] += av[i] * bv[j];
        }
        __syncthreads();
    }
#pragma unroll
    for (int i = 0; i < 4; ++i)
#pragma unroll
        for (int j = 0; j < 4; ++j)
            parts[((((size_t)ks * B_ + b) * R_) + ty * 4 + i) * C_ + n0 + tx * 4 + j] = acc[i][j];
}

__global__ __launch_bounds__(256) void compress_reduce(const float* __restrict__ parts,
                                                       float* __restrict__ px)
{
    const size_t i = (size_t)blockIdx.x * 256 + threadIdx.x;
    constexpr size_t S = (size_t)B_ * R_ * C_;
    px[i] = parts[i] + parts[i + S] + parts[i + 2 * S] + parts[i + 3 * S];
}

// qkv fused-N GEMM
__global__ __launch_bounds__(256) void qkv_gemm(
    const float* __restrict__ px,
    const float* __restrict__ Wq, const float* __restrict__ bq,
    const float* __restrict__ Wk, const float* __restrict__ bk,
    const float* __restrict__ Wv, const float* __restrict__ bv,
    float* __restrict__ q, float* __restrict__ k, float* __restrict__ v)
{
    __shared__ float As[16][68];
    __shared__ float Bs[16][64];
    const int tid = threadIdx.x;
    const int tx = tid & 15, ty = tid >> 4;
    const int bx = blockIdx.x;
    const int m0 = blockIdx.y * 64;
    const float* W; const float* bias; float* dst; int Nloc, ncol0;
    if (bx == 0)      { W = Wq; bias = bq; dst = q; Nloc = 64;   ncol0 = 0; }
    else if (bx == 1) { W = Wk; bias = bk; dst = k; Nloc = 64;   ncol0 = 0; }
    else              { W = Wv; bias = bv; dst = v; Nloc = H_;   ncol0 = (bx - 2) * 64; }

    float acc[4][4] = {};
    for (int k0 = 0; k0 < C_; k0 += 16) {
#pragma unroll
        for (int s = 0; s < 4; ++s) {
            int idx = tid + s * 256;
            int am = idx >> 4, ak = idx & 15;
            As[ak][am] = px[(size_t)(m0 + am) * C_ + k0 + ak];
        }
#pragma unroll
        for (int s = 0; s < 4; ++s) {
            int idx = tid + s * 256;
            int kk = idx >> 6, bn = idx & 63;
            Bs[kk][bn] = W[(size_t)(k0 + kk) * Nloc + ncol0 + bn];
        }
        __syncthreads();
#pragma unroll
        for (int kk = 0; kk < 16; ++kk) {
            float av[4], bv4[4];
            *(float4*)av = *(const float4*)&As[kk][ty * 4];
            *(float4*)bv4 = *(const float4*)&Bs[kk][tx * 4];
#pragma unroll
            for (int i = 0; i < 4; ++i)
#pragma unroll
                for (int j = 0; j < 4; ++j) acc[i][j] += av[i] * bv4[j];
        }
        __syncthreads();
    }
#pragma unroll
    for (int i = 0; i < 4; ++i) {
        int m = m0 + ty * 4 + i;
#pragma unroll
        for (int j = 0; j < 4; ++j) {
            int n = ncol0 + tx * 4 + j;
            dst[(size_t)m * Nloc + n] = siluf(acc[i][j] + bias[n]);
        }
    }
}

// scores + softmax -> alpha
__global__ __launch_bounds__(64) void attn_scores(
    const float* __restrict__ q, const float* __restrict__ k,
    const float* __restrict__ preS, float* __restrict__ alpha)
{
    const int b = blockIdx.x >> 6, r = blockIdx.x & 63;
    const int s = threadIdx.x;
    const float* qr = q + ((size_t)b * R_ + r) * DK_;
    const float* ks = k + ((size_t)b * R_ + s) * DK_;
    float acc = 0.f;
#pragma unroll
    for (int d = 0; d < DK_; ++d) acc += qr[d] * ks[d];
    acc = acc * 0.125f + preS[((size_t)b * R_ + r) * R_ + s];
    float mx = acc;
#pragma unroll
    for (int o = 32; o > 0; o >>= 1) mx = fmaxf(mx, __shfl_xor(mx, o, 64));
    float e = __expf(acc - mx);
    float sm = e;
#pragma unroll
    for (int o = 32; o > 0; o >>= 1) sm += __shfl_xor(sm, o, 64);
    alpha[((size_t)b * R_ + r) * R_ + s] = e / sm;
}

// z_small = alpha @ v.  MODE 0: zs fp32 [b][r][h]; MODE 1: zsT bf16 [b][h][r].
template <int MODE>
__global__ __launch_bounds__(256) void attn_z(const float* __restrict__ alpha,
                                              const float* __restrict__ v,
                                              float* __restrict__ zsF,
                                              ushort* __restrict__ zsT)
{
    const int b = blockIdx.x >> 6, r = blockIdx.x & 63;
    const int t = threadIdx.x;
    __shared__ float al[R_];
    if (t < R_) al[t] = alpha[((size_t)b * R_ + r) * R_ + t];
    __syncthreads();
    float acc[4] = {};
    for (int s = 0; s < R_; ++s) {
        float a = al[s];
        const float* vr = v + ((size_t)b * R_ + s) * H_;
#pragma unroll
        for (int j = 0; j < 4; ++j) acc[j] += a * vr[t + j * 256];
    }
#pragma unroll
    for (int j = 0; j < 4; ++j) {
        const int h = t + j * 256;
        if (MODE == 0) zsF[((size_t)b * R_ + r) * H_ + h] = acc[j];
        else           zsT[((size_t)b * H_ + h) * R_ + r] = bfbits(acc[j]);
    }
}

// Row layernorm of bf16 y -> fp32 out
__global__ __launch_bounds__(256) void layernorm(const __hip_bfloat16* __restrict__ y,
                                                 const float* __restrict__ gamma,
                                                 const float* __restrict__ beta,
                                                 float* __restrict__ out)
{
    const size_t m = blockIdx.x;
    const int t = threadIdx.x;
    const __hip_bfloat16* yr = y + m * C_;
    float v0 = __bfloat162float(yr[t]), v1 = __bfloat162float(yr[t + 256]);
    __shared__ float rs[256], rq[256];
    rs[t] = v0 + v1;
    rq[t] = v0 * v0 + v1 * v1;
    __syncthreads();
    for (int o = 128; o > 0; o >>= 1) {
        if (t < o) { rs[t] += rs[t + o]; rq[t] += rq[t + o]; }
        __syncthreads();
    }
    const float mu = rs[0] * (1.0f / C_);
    const float var = rq[0] * (1.0f / C_) - mu * mu;
    const float inv = rsqrtf(var + 1e-5f);
    out[m * C_ + t] = (v0 - mu) * inv * gamma[t] + beta[t];
    out[m * C_ + t + 256] = (v1 - mu) * inv * gamma[t + 256] + beta[t + 256];
}

extern "C" void kernel_launch(void* const* d_in, const int* in_sizes, int n_in,
                              void* d_out, int out_size, void* d_ws, size_t ws_size,
                              hipStream_t stream)
{
    using bf16 = __hip_bfloat16;
    const float* x      = (const float*)d_in[0];
    const int*  maskPAD = (const int*)d_in[1];
    const float* preS   = (const float*)d_in[2];
    const float* Wp     = (const float*)d_in[3];
    const float* bp     = (const float*)d_in[4];
    const float* Wq     = (const float*)d_in[5];
    const float* bq     = (const float*)d_in[6];
    const float* Wk     = (const float*)d_in[7];
    const float* bk     = (const float*)d_in[8];
    const float* Wv     = (const float*)d_in[9];
    const float* bv     = (const float*)d_in[10];
    const float* Wu     = (const float*)d_in[11];
    const float* bu     = (const float*)d_in[12];
    const float* Wo     = (const float*)d_in[13];
    const float* bo     = (const float*)d_in[14];
    const float* gamma  = (const float*)d_in[15];
    const float* beta   = (const float*)d_in[16];
    float* out          = (float*)d_out;

    char* ws = (char*)d_ws;
    const bool bigWS = ws_size >= (size_t)52 * 1024 * 1024;  // proven taken (round 4/5 profiles)

    if (bigWS) {
        // ---- layout: gate 32 MB | pool 17.4 MB | Wut+Wot 2 MB ----
        bf16* gate = (bf16*)ws;                                 // M*H bf16 (zg in-place later)
        char* pool = ws + (size_t)M_ * H_ * 2;
        float* pScore = (float*)pool;                           // reused: compress parts
        float* pAL   = pScore + (size_t)M_ * R_;
        float* pAR   = pAL    + (size_t)M_ * R_;                // used as ushort bf16 here
        float* px    = pAR    + (size_t)M_ * R_;
        float* q     = px     + (size_t)B_ * R_ * C_;
        float* kk    = q      + (size_t)B_ * R_ * DK_;
        float* vv    = kk     + (size_t)B_ * R_ * DK_;
        float* alpha = vv     + (size_t)B_ * R_ * H_;
        float* zs    = alpha  + (size_t)B_ * R_ * R_;           // used as zsT bf16 [B,H,R]
        ushort* pAR16 = (ushort*)pAR;
        ushort* zsT16 = (ushort*)zs;
        ushort* x16  = (ushort*)pool;                           // x bf16, dead before pScore write
        bf16*  y     = (bf16*)pool;                             // pre-LN y, aliases dead pool
        ushort* Wut  = (ushort*)(pool + 18221568);              // [H, C] bf16
        ushort* Wot  = Wut + (size_t)C_ * H_;                   // [C, H] bf16

        // prep: x -> bf16 ; Wu,Wo -> transposed bf16
        f32_to_bf16_k<<<(M_ * C_) / 1024, 256, 0, stream>>>(x, x16);
        transpose_to_bf16<<<dim3(H_ / 32, C_ / 32), 256, 0, stream>>>(Wu, Wut, C_, H_);
        transpose_to_bf16<<<dim3(C_ / 32, H_ / 32), 256, 0, stream>>>(Wo, Wot, H_, C_);

        // 1) gate = silu(x @ Wu + bu)  [MFMA, grid 16*128 swizzled]
        mfma_gemm2<0><<<(H_ / 64) * (M_ / 128), 256, 0, stream>>>(
            x16, Wut, bu, nullptr, nullptr, (ushort*)gate, H_, C_, H_ / 64, 0);
        // 2) pScore = x @ Wp + bp, mask  (pool writes ok - x16 dead after Wu)
        gemm64<float, float, float, 0, 1><<<dim3(R_ / 64, M_ / 64), 256, 0, stream>>>(
            x, Wp, bp, maskPAD, (const float*)nullptr, pScore, nullptr, R_, C_, 0);
        softmaxL<<<B_ * R_, 256, 0, stream>>>(pScore, pAL);
        softmaxR<1><<<M_, 64, 0, stream>>>(pScore, nullptr, pAR16);
        compress_part<<<dim3(C_ / 64, 4, B_), 256, 0, stream>>>(pAL, x, pScore);
        compress_reduce<<<(B_ * R_ * C_) / 256, 256, 0, stream>>>(pScore, px);
        qkv_gemm<<<dim3(2 + H_ / 64, (B_ * R_) / 64), 256, 0, stream>>>(
            px, Wq, bq, Wk, bk, Wv, bv, q, kk, vv);
        attn_scores<<<B_ * R_, 64, 0, stream>>>(q, kk, preS, alpha);
        attn_z<1><<<B_ * R_, 256, 0, stream>>>(alpha, vv, nullptr, zsT16);
        // 9) zg = gate * (pAR @ zs)  [MFMA K=64, batched B, in-place over gate]
        mfma_gemm2<3><<<(H_ / 64) * (M_ / 128), 256, 0, stream>>>(
            pAR16, zsT16, nullptr, nullptr, (ushort*)gate, (ushort*)gate,
            H_, R_, H_ / 64, (long)H_ * R_);
        // 10) y = x + zg @ Wo + bo  [MFMA, fp32 residual, grid 8*128]
        mfma_gemm2<2><<<(C_ / 64) * (M_ / 128), 256, 0, stream>>>(
            (ushort*)gate, Wot, bo, x, nullptr, (ushort*)y, C_, H_, C_ / 64, 0);
        layernorm<<<M_, 256, 0, stream>>>(y, gamma, beta, out);
    } else {
        // ---- Compact plan (~23.4 MiB), SIMT per-batch (dead in practice) ----
        float* pScore = (float*)ws;
        float* pAL   = pScore + (size_t)M_ * R_;
        float* pAR   = pAL    + (size_t)M_ * R_;
        float* px    = pAR    + (size_t)M_ * R_;
        float* q     = px     + (size_t)B_ * R_ * C_;
        float* kk    = q      + (size_t)B_ * R_ * DK_;
        float* vv    = kk     + (size_t)B_ * R_ * DK_;
        float* alpha = vv     + (size_t)B_ * R_ * H_;
        float* zs    = alpha  + (size_t)B_ * R_ * R_;
        bf16* gate_b = (bf16*)(zs + (size_t)B_ * R_ * H_);
        bf16* y_b    = (bf16*)((char*)gate_b + (size_t)L_ * H_ * 2);

        gemm64<float, float, float, 0, 1><<<dim3(R_ / 64, M_ / 64), 256, 0, stream>>>(
            x, Wp, bp, maskPAD, (const float*)nullptr, pScore, nullptr, R_, C_, 0);
        softmaxL<<<B_ * R_, 256, 0, stream>>>(pScore, pAL);
        softmaxR<0><<<M_, 64, 0, stream>>>(pScore, pAR, nullptr);
        compress_part<<<dim3(C_ / 64, 4, B_), 256, 0, stream>>>(pAL, x, pScore);
        compress_reduce<<<(B_ * R_ * C_) / 256, 256, 0, stream>>>(pScore, px);
        qkv_gemm<<<dim3(2 + H_ / 64, (B_ * R_) / 64), 256, 0, stream>>>(
            px, Wq, bq, Wk, bk, Wv, bv, q, kk, vv);
        attn_scores<<<B_ * R_, 64, 0, stream>>>(q, kk, preS, alpha);
        attn_z<0><<<B_ * R_, 256, 0, stream>>>(alpha, vv, zs, nullptr);

        for (int b = 0; b < B_; ++b) {
            const float* xb = x + (size_t)b * L_ * C_;
            gemm64<float, float, float, 1, 0><<<dim3(H_ / 64, L_ / 64), 256, 0, stream>>>(
                xb, Wu, bu, nullptr, (const float*)nullptr, nullptr, gate_b, H_, C_, 0);
            gemm64<float, float, bf16, 0, 3><<<dim3(H_ / 64, L_ / 64), 256, 0, stream>>>(
                pAR + (size_t)b * L_ * R_, zs + (size_t)b * R_ * H_,
                nullptr, nullptr, gate_b, nullptr, gate_b, H_, R_, 0);
            gemm64<bf16, float, float, 0, 2><<<dim3(C_ / 64, L_ / 64), 256, 0, stream>>>(
                gate_b, Wo, bo, nullptr, xb, nullptr, y_b, C_, H_, 0);
            layernorm<<<L_, 256, 0, stream>>>(y_b, gamma, beta, out + (size_t)b * L_ * C_);
        }
    }
}